// Round 1
// baseline (116.317 us; speedup 1.0000x reference)
//
#include <hip/hip_runtime.h>
#include <stdint.h>
#include <stddef.h>

#define S_LEN 2048
#define DMODEL 1024
#define NHEAD 16
#define HDIM 64
#define WINSZ 256
#define MROWS 4096
#define NQKV 3072

typedef __bf16 bf16x8 __attribute__((ext_vector_type(8)));
typedef float f32x4 __attribute__((ext_vector_type(4)));
typedef unsigned short us4 __attribute__((ext_vector_type(4)));
typedef unsigned short us8 __attribute__((ext_vector_type(8)));

__device__ __forceinline__ unsigned short f2b(float f) {
  union { float f; unsigned u; } v; v.f = f;
  unsigned u = v.u;
  unsigned r = (u + 0x7FFFu + ((u >> 16) & 1u)) >> 16;
  return (unsigned short)r;
}
__device__ __forceinline__ float b2f(unsigned short h) {
  union { unsigned u; float f; } v; v.u = ((unsigned)h) << 16;
  return v.f;
}
__device__ __forceinline__ void storev(float* p, float v) { *p = v; }
__device__ __forceinline__ void storev(unsigned short* p, float v) { *p = f2b(v); }

// ---------------- prep kernels ----------------

__global__ void cast_x_kernel(const float* __restrict__ x, unsigned short* __restrict__ xb) {
  int i = (blockIdx.x * blockDim.x + threadIdx.x) * 4;
  float4 v = *reinterpret_cast<const float4*>(x + i);
  us4 o;
  o[0] = f2b(v.x); o[1] = f2b(v.y); o[2] = f2b(v.z); o[3] = f2b(v.w);
  *reinterpret_cast<us4*>(xb + i) = o;
}

// W: [1024][1024] f32 row-major (k-major rows). Wt: [n][k] bf16.
__global__ void transpose_cast_kernel(const float* __restrict__ W, unsigned short* __restrict__ Wt) {
  __shared__ float tile[32][33];
  int n0 = blockIdx.x * 32, k0 = blockIdx.y * 32;
  int tx = threadIdx.x, ty = threadIdx.y;
#pragma unroll
  for (int i = 0; i < 32; i += 8)
    tile[ty + i][tx] = W[(size_t)(k0 + ty + i) * DMODEL + n0 + tx];
  __syncthreads();
#pragma unroll
  for (int i = 0; i < 32; i += 8)
    Wt[(size_t)(n0 + ty + i) * DMODEL + k0 + tx] = f2b(tile[tx][ty + i]);
}

__global__ void pack_bias_kernel(const float* __restrict__ bq, const float* __restrict__ bk,
                                 const float* __restrict__ bv, float* __restrict__ bqkv) {
  int i = blockIdx.x * blockDim.x + threadIdx.x;
  if (i < DMODEL) {
    bqkv[i] = bq[i];
    bqkv[DMODEL + i] = bk[i];
    bqkv[2 * DMODEL + i] = bv[i];
  }
}

// ---------------- GEMM: C[M][N] = A[M][K](bf16) * Bt[N][K](bf16)^T + bias ----------------
// 128x128 tile, 256 threads (4 waves, 2x2), each wave 64x64 = 4x4 frags of 16x16x32 MFMA.

template <typename OutT>
__global__ __launch_bounds__(256) void gemm_bias_kernel(
    const unsigned short* __restrict__ A, const unsigned short* __restrict__ Bt,
    const float* __restrict__ bias, OutT* __restrict__ C, int N, int K) {
  __shared__ unsigned short As[128 * 72];
  __shared__ unsigned short Bs[128 * 72];
  const int tid = threadIdx.x;
  const int m0 = blockIdx.y * 128, n0 = blockIdx.x * 128;
  const int w = tid >> 6, l = tid & 63;
  const int wm = (w >> 1) * 64, wn = (w & 1) * 64;
  const int lr = l & 15, lg = l >> 4;

  f32x4 acc[4][4];
#pragma unroll
  for (int i = 0; i < 4; i++)
#pragma unroll
    for (int j = 0; j < 4; j++) acc[i][j] = (f32x4){0.f, 0.f, 0.f, 0.f};

  for (int k0 = 0; k0 < K; k0 += 64) {
    __syncthreads();
#pragma unroll
    for (int i = 0; i < 4; i++) {
      int idx = tid + i * 256;
      int row = idx >> 3, c8 = (idx & 7) * 8;
      *reinterpret_cast<us8*>(&As[row * 72 + c8]) =
          *reinterpret_cast<const us8*>(&A[(size_t)(m0 + row) * K + k0 + c8]);
      *reinterpret_cast<us8*>(&Bs[row * 72 + c8]) =
          *reinterpret_cast<const us8*>(&Bt[(size_t)(n0 + row) * K + k0 + c8]);
    }
    __syncthreads();
#pragma unroll
    for (int kk = 0; kk < 64; kk += 32) {
      bf16x8 a[4], b[4];
#pragma unroll
      for (int f = 0; f < 4; f++)
        a[f] = *reinterpret_cast<const bf16x8*>(&As[(wm + f * 16 + lr) * 72 + kk + lg * 8]);
#pragma unroll
      for (int f = 0; f < 4; f++)
        b[f] = *reinterpret_cast<const bf16x8*>(&Bs[(wn + f * 16 + lr) * 72 + kk + lg * 8]);
#pragma unroll
      for (int i = 0; i < 4; i++)
#pragma unroll
        for (int j = 0; j < 4; j++)
          acc[i][j] = __builtin_amdgcn_mfma_f32_16x16x32_bf16(a[i], b[j], acc[i][j], 0, 0, 0);
    }
  }

#pragma unroll
  for (int i = 0; i < 4; i++) {
    int row = m0 + wm + i * 16 + lg * 4;
#pragma unroll
    for (int j = 0; j < 4; j++) {
      int col = n0 + wn + j * 16 + lr;
      float bsv = bias[col];
#pragma unroll
      for (int r = 0; r < 4; r++) {
        float vv = acc[i][j][r] + bsv;
        storev(&C[(size_t)(row + r) * N + col], vv);
      }
    }
  }
}

// ---------------- windowed flash attention ----------------
// Block: (tile, h, b). 4 waves x 16 q-rows = 64 rows. 5 key chunks of 64.

__global__ __launch_bounds__(256) void attn_kernel(const unsigned short* __restrict__ qkv,
                                                   unsigned short* __restrict__ attnb) {
  __shared__ unsigned short Ks[64 * 72];   // K chunk, row j, col d
  __shared__ unsigned short Vt[64 * 72];   // V chunk transposed: row d, col j
  __shared__ unsigned short Ps[4][16 * 72];// per-wave P tile, row q, col j

  const int tid = threadIdx.x;
  const int i0 = blockIdx.x * 64;
  const int h = blockIdx.y;
  const int b = blockIdx.z;
  const int w = tid >> 6, l = tid & 63;
  const int lr = l & 15, lg = l >> 4;
  const size_t rowb = (size_t)b * S_LEN;

  // Q fragments (A-operand): row = i0 + w*16 + lr, k = kf*32 + lg*8 + e
  const unsigned short* qptr = qkv + (rowb + i0 + w * 16 + lr) * NQKV + h * HDIM;
  bf16x8 qa[2];
  qa[0] = *reinterpret_cast<const bf16x8*>(qptr + lg * 8);
  qa[1] = *reinterpret_cast<const bf16x8*>(qptr + 32 + lg * 8);

  f32x4 accO[4];
#pragma unroll
  for (int f = 0; f < 4; f++) accO[f] = (f32x4){0.f, 0.f, 0.f, 0.f};
  float Mv[4], Lv[4];
#pragma unroll
  for (int r = 0; r < 4; r++) { Mv[r] = -1e30f; Lv[r] = 0.f; }

  for (int c = 0; c < 5; c++) {
    int j0c = i0 - WINSZ + c * 64;
    if (j0c + 63 < 0) continue;  // uniform across block
    __syncthreads();
    // stage K (row-major) and V (transposed)
    {
      int d4 = (tid & 15) * 4;
      int jl0 = tid >> 4;
#pragma unroll
      for (int it = 0; it < 4; it++) {
        int jl = jl0 + it * 16;
        int jg = j0c + jl;
        us4 kv = (us4){0, 0, 0, 0}, vv = (us4){0, 0, 0, 0};
        if (jg >= 0) {
          const unsigned short* kp = qkv + (rowb + jg) * NQKV + DMODEL + h * HDIM + d4;
          kv = *reinterpret_cast<const us4*>(kp);
          vv = *reinterpret_cast<const us4*>(kp + DMODEL);
        }
        *reinterpret_cast<us4*>(&Ks[jl * 72 + d4]) = kv;
        Vt[(d4 + 0) * 72 + jl] = vv[0];
        Vt[(d4 + 1) * 72 + jl] = vv[1];
        Vt[(d4 + 2) * 72 + jl] = vv[2];
        Vt[(d4 + 3) * 72 + jl] = vv[3];
      }
    }
    __syncthreads();

    // S = Q K^T  (S rows: wave's 16 q-rows; cols: 64 chunk keys)
    f32x4 sa[4];
#pragma unroll
    for (int f = 0; f < 4; f++) sa[f] = (f32x4){0.f, 0.f, 0.f, 0.f};
#pragma unroll
    for (int f = 0; f < 4; f++) {
      bf16x8 k0v = *reinterpret_cast<const bf16x8*>(&Ks[(f * 16 + lr) * 72 + lg * 8]);
      bf16x8 k1v = *reinterpret_cast<const bf16x8*>(&Ks[(f * 16 + lr) * 72 + 32 + lg * 8]);
      sa[f] = __builtin_amdgcn_mfma_f32_16x16x32_bf16(qa[0], k0v, sa[f], 0, 0, 0);
      sa[f] = __builtin_amdgcn_mfma_f32_16x16x32_bf16(qa[1], k1v, sa[f], 0, 0, 0);
    }
    // scale + mask
#pragma unroll
    for (int f = 0; f < 4; f++) {
      int jg = j0c + f * 16 + lr;
#pragma unroll
      for (int r = 0; r < 4; r++) {
        int irow = i0 + w * 16 + lg * 4 + r;
        float s = sa[f][r] * 0.125f;
        bool ok = (jg >= 0) && (jg <= irow) && (jg >= irow - WINSZ);
        sa[f][r] = ok ? s : -1e30f;
      }
    }
    // online softmax
    float pm[4];
#pragma unroll
    for (int r = 0; r < 4; r++) {
      float m = fmaxf(fmaxf(sa[0][r], sa[1][r]), fmaxf(sa[2][r], sa[3][r]));
#pragma unroll
      for (int off = 1; off < 16; off <<= 1) m = fmaxf(m, __shfl_xor(m, off));
      pm[r] = m;
    }
#pragma unroll
    for (int r = 0; r < 4; r++) {
      float Mn = fmaxf(Mv[r], pm[r]);
      float sc = __expf(Mv[r] - Mn);
      Mv[r] = Mn;
      Lv[r] *= sc;
#pragma unroll
      for (int f = 0; f < 4; f++) accO[f][r] *= sc;
    }
    float rs[4] = {0.f, 0.f, 0.f, 0.f};
#pragma unroll
    for (int f = 0; f < 4; f++) {
#pragma unroll
      for (int r = 0; r < 4; r++) {
        float p = __expf(sa[f][r] - Mv[r]);
        rs[r] += p;
        Ps[w][(lg * 4 + r) * 72 + f * 16 + lr] = f2b(p);
      }
    }
#pragma unroll
    for (int r = 0; r < 4; r++) {
      float s = rs[r];
#pragma unroll
      for (int off = 1; off < 16; off <<= 1) s += __shfl_xor(s, off);
      Lv[r] += s;
    }
    // PV: accO += P * V
    bf16x8 pa0 = *reinterpret_cast<const bf16x8*>(&Ps[w][lr * 72 + lg * 8]);
    bf16x8 pa1 = *reinterpret_cast<const bf16x8*>(&Ps[w][lr * 72 + 32 + lg * 8]);
#pragma unroll
    for (int f = 0; f < 4; f++) {
      bf16x8 v0 = *reinterpret_cast<const bf16x8*>(&Vt[(f * 16 + lr) * 72 + lg * 8]);
      bf16x8 v1 = *reinterpret_cast<const bf16x8*>(&Vt[(f * 16 + lr) * 72 + 32 + lg * 8]);
      accO[f] = __builtin_amdgcn_mfma_f32_16x16x32_bf16(pa0, v0, accO[f], 0, 0, 0);
      accO[f] = __builtin_amdgcn_mfma_f32_16x16x32_bf16(pa1, v1, accO[f], 0, 0, 0);
    }
  }

#pragma unroll
  for (int f = 0; f < 4; f++) {
#pragma unroll
    for (int r = 0; r < 4; r++) {
      float o = accO[f][r] / Lv[r];
      int row = i0 + w * 16 + lg * 4 + r;
      attnb[(rowb + row) * DMODEL + h * HDIM + f * 16 + lr] = f2b(o);
    }
  }
}

// ---------------- launch ----------------

extern "C" void kernel_launch(void* const* d_in, const int* in_sizes, int n_in,
                              void* d_out, int out_size, void* d_ws, size_t ws_size,
                              hipStream_t stream) {
  const float* x = (const float*)d_in[0];
  const float* Wq = (const float*)d_in[1];
  const float* bq = (const float*)d_in[2];
  const float* Wk = (const float*)d_in[3];
  const float* bk = (const float*)d_in[4];
  const float* Wv = (const float*)d_in[5];
  const float* bv = (const float*)d_in[6];
  const float* Wo = (const float*)d_in[7];
  const float* bo = (const float*)d_in[8];
  float* out = (float*)d_out;

  unsigned short* xb = (unsigned short*)d_ws;                       // 4096*1024
  unsigned short* WqkvT = xb + (size_t)MROWS * DMODEL;              // 3*1024*1024
  unsigned short* WoT = WqkvT + (size_t)3 * DMODEL * DMODEL;        // 1024*1024
  unsigned short* QKV = WoT + (size_t)DMODEL * DMODEL;              // 4096*3072
  unsigned short* attnb = QKV + (size_t)MROWS * NQKV;               // 4096*1024
  float* bqkv = (float*)(attnb + (size_t)MROWS * DMODEL);           // 3072 f32

  cast_x_kernel<<<4096, 256, 0, stream>>>(x, xb);
  dim3 tb(32, 8);
  transpose_cast_kernel<<<dim3(32, 32), tb, 0, stream>>>(Wq, WqkvT);
  transpose_cast_kernel<<<dim3(32, 32), tb, 0, stream>>>(Wk, WqkvT + (size_t)DMODEL * DMODEL);
  transpose_cast_kernel<<<dim3(32, 32), tb, 0, stream>>>(Wv, WqkvT + (size_t)2 * DMODEL * DMODEL);
  transpose_cast_kernel<<<dim3(32, 32), tb, 0, stream>>>(Wo, WoT);
  pack_bias_kernel<<<4, 256, 0, stream>>>(bq, bk, bv, bqkv);

  gemm_bias_kernel<unsigned short><<<dim3(NQKV / 128, MROWS / 128), 256, 0, stream>>>(
      xb, WqkvT, bqkv, QKV, NQKV, DMODEL);

  attn_kernel<<<dim3(S_LEN / 64, NHEAD, 2), 256, 0, stream>>>(QKV, attnb);

  gemm_bias_kernel<float><<<dim3(DMODEL / 128, MROWS / 128), 256, 0, stream>>>(
      attnb, WoT, bo, out, DMODEL, DMODEL);
}